// Round 10
// baseline (2552.693 us; speedup 1.0000x reference)
//
#include <hip/hip_runtime.h>
#include <stdint.h>

#define BB 8
#define NN 2048
#define DD 64
#define REGv 0.1f
#define NUM_ITERS 50
#define EPS_NORM 1e-8f
#define EPS_SINK 1e-10f

typedef float f4 __attribute__((ext_vector_type(4)));
typedef __attribute__((address_space(1))) const void GV;
typedef __attribute__((address_space(3))) void LV;

__device__ __forceinline__ float dotf4(f4 a, f4 b) {
    return a.x * b.x + a.y * b.y + a.z * b.z + a.w * b.w;
}

// ---------------- init: maxd2 = 0, barrier counters = 0 ----------------
// counters: 2 phases x 50 iters x 8 batches, padded to 32 uints (128 B)
__global__ void init_k(unsigned* maxd, unsigned* bar) {
    int t = blockIdx.x * 256 + threadIdx.x;
    if (t < BB) maxd[t] = 0u;
    if (t < 2 * NUM_ITERS * 8 * 32) bar[t] = 0u;
}

// ---------------- row squared norms (one wave per row) ----------------
__global__ void sq_k(const float* __restrict__ x0, const float* __restrict__ x1,
                     float* __restrict__ sq0, float* __restrict__ sq1) {
    int w = (blockIdx.x * 256 + threadIdx.x) >> 6;
    int lane = threadIdx.x & 63;
    if (w >= 2 * BB * NN) return;
    const float* src = (w < BB * NN) ? x0 : x1;
    int r = (w < BB * NN) ? w : w - BB * NN;
    float val = src[(size_t)r * DD + lane];
    float s = val * val;
    #pragma unroll
    for (int off = 32; off; off >>= 1) s += __shfl_xor(s, off);
    if (lane == 0) ((w < BB * NN) ? sq0 : sq1)[r] = s;
}

// ---------------- fused cdist: WRITE=0 -> max(d2); WRITE=1 -> K=exp ----------------
template<int WRITE>
__global__ __launch_bounds__(256) void distc_k(const float* __restrict__ x0,
                                               const float* __restrict__ x1,
                                               const float* __restrict__ sq0,
                                               const float* __restrict__ sq1,
                                               float* __restrict__ Kd,
                                               unsigned* __restrict__ maxd) {
    __shared__ float x0s[128 * 64];
    __shared__ float x1t[64 * 68];
    __shared__ float wred[4];
    int bid = blockIdx.x;
    int b = bid >> 9;
    int tile = bid & 511;
    int ti = tile >> 5, tj = tile & 31;
    int i0 = ti * 128, j0 = tj * 64;
    int t = threadIdx.x;

    const float4* g0 = (const float4*)(x0 + ((size_t)b * NN + i0) * DD);
    #pragma unroll
    for (int rep = 0; rep < 8; rep++) {
        int e = rep * 256 + t;
        int row = e >> 4, c4 = e & 15;
        int pc = c4 ^ ((row >> 3) & 3);     // XOR swizzle
        *(float4*)&x0s[row * 64 + pc * 4] = g0[row * 16 + c4];
    }
    const float4* g1 = (const float4*)(x1 + ((size_t)b * NN + j0) * DD);
    #pragma unroll
    for (int rep = 0; rep < 4; rep++) {
        int e = rep * 256 + t;
        int row = e >> 4, c4 = e & 15;
        float4 a = g1[row * 16 + c4];
        x1t[(c4 * 4 + 0) * 68 + row] = a.x;
        x1t[(c4 * 4 + 1) * 68 + row] = a.y;
        x1t[(c4 * 4 + 2) * 68 + row] = a.z;
        x1t[(c4 * 4 + 3) * 68 + row] = a.w;
    }
    __syncthreads();

    int tx = t & 15, ty = t >> 4;
    float4 acc4[8];
    #pragma unroll
    for (int di = 0; di < 8; di++) acc4[di] = make_float4(0.f, 0.f, 0.f, 0.f);

    #pragma unroll
    for (int k4 = 0; k4 < 16; k4++) {
        float4 b0 = *(const float4*)&x1t[(k4 * 4 + 0) * 68 + tx * 4];
        float4 b1 = *(const float4*)&x1t[(k4 * 4 + 1) * 68 + tx * 4];
        float4 b2 = *(const float4*)&x1t[(k4 * 4 + 2) * 68 + tx * 4];
        float4 b3 = *(const float4*)&x1t[(k4 * 4 + 3) * 68 + tx * 4];
        int pk = (k4 ^ (ty & 3)) << 2;
        #pragma unroll
        for (int di = 0; di < 8; di++) {
            float4 a = *(const float4*)&x0s[(ty * 8 + di) * 64 + pk];
            acc4[di].x += a.x * b0.x + a.y * b1.x + a.z * b2.x + a.w * b3.x;
            acc4[di].y += a.x * b0.y + a.y * b1.y + a.z * b2.y + a.w * b3.y;
            acc4[di].z += a.x * b0.z + a.y * b1.z + a.z * b2.z + a.w * b3.z;
            acc4[di].w += a.x * b0.w + a.y * b1.w + a.z * b2.w + a.w * b3.w;
        }
    }

    int ib = b * NN + i0 + ty * 8;
    float4 s1 = *(const float4*)&sq1[b * NN + j0 + tx * 4];

    if (WRITE) {
        float mv = sqrtf(__uint_as_float(maxd[b])) + EPS_NORM;
        #pragma unroll
        for (int di = 0; di < 8; di++) {
            float s0 = sq0[ib + di];
            float4 o;
            o.x = expf(-((sqrtf(fmaxf(s0 + s1.x - 2.f * acc4[di].x, 0.f)) / mv) / REGv));
            o.y = expf(-((sqrtf(fmaxf(s0 + s1.y - 2.f * acc4[di].y, 0.f)) / mv) / REGv));
            o.z = expf(-((sqrtf(fmaxf(s0 + s1.z - 2.f * acc4[di].z, 0.f)) / mv) / REGv));
            o.w = expf(-((sqrtf(fmaxf(s0 + s1.w - 2.f * acc4[di].w, 0.f)) / mv) / REGv));
            *(float4*)&Kd[(size_t)(ib + di) * NN + j0 + tx * 4] = o;
        }
    } else {
        float lm = 0.0f;
        #pragma unroll
        for (int di = 0; di < 8; di++) {
            float s0 = sq0[ib + di];
            lm = fmaxf(lm, fmaxf(s0 + s1.x - 2.f * acc4[di].x, 0.f));
            lm = fmaxf(lm, fmaxf(s0 + s1.y - 2.f * acc4[di].y, 0.f));
            lm = fmaxf(lm, fmaxf(s0 + s1.z - 2.f * acc4[di].z, 0.f));
            lm = fmaxf(lm, fmaxf(s0 + s1.w - 2.f * acc4[di].w, 0.f));
        }
        #pragma unroll
        for (int off = 32; off; off >>= 1) lm = fmaxf(lm, __shfl_xor(lm, off));
        if ((t & 63) == 0) wred[t >> 6] = lm;
        __syncthreads();
        if (t == 0) {
            float m = fmaxf(fmaxf(wred[0], wred[1]), fmaxf(wred[2], wred[3]));
            atomicMax(&maxd[b], __float_as_uint(m));  // d2 >= 0: uint cmp == float cmp
        }
    }
}

// ---------------- per-batch barrier (32 blocks, one-shot counter) ----------------
__device__ __forceinline__ void gbar(unsigned* c, int t, unsigned n) {
    __syncthreads();
    if (t == 0) {
        __threadfence();                 // release (agent scope)
        atomicAdd(c, 1u);
        while (__hip_atomic_load(c, __ATOMIC_RELAXED, __HIP_MEMORY_SCOPE_AGENT) < n)
            __builtin_amdgcn_s_sleep(2);
        __threadfence();                 // acquire
    }
    __syncthreads();
}

// ---------------- persistent Sinkhorn: de-pinned batches + async LDS ring ----------------
// 256 blocks x 512 threads (8 waves), 1 block/CU (147 KB LDS).
// Block q: batch b=q>>5 (spread across XCDs), group g=q&31, rows g*64..g*64+63.
// Chunk c (8 rows): wave w owns row c*8+w entirely -> u is wave-local.
// Staging always runs 2 chunks ahead (wrapping into the next iteration) so DMA
// stays saturated across the barrier/vred phase. Slice-vred + broadcast (2 gbars).
__global__ __launch_bounds__(512)
void persist_k(const float* __restrict__ Kd,
               float* __restrict__ partial,
               float* __restrict__ vglob,
               float* __restrict__ uglob,
               unsigned* __restrict__ bar) {
    __shared__ f4 S[2][8][512];     // 128 KB staging ring
    __shared__ f4 vbuf4[512];       // 8 KB
    __shared__ f4 sgbuf[512];       // 8 KB

    const int t = threadIdx.x;
    const int l = t & 63;
    const int w = t >> 6;
    const int q = blockIdx.x;
    const int b = q >> 5;           // de-pinned: batch spread over XCDs
    const int g = q & 31;
    const size_t rowbase = (size_t)b * NN + (size_t)g * 64;

    vbuf4[t] = (f4){1.0f / NN, 1.0f / NN, 1.0f / NN, 1.0f / NN};
    __syncthreads();

#define STAGE(c_) do { \
    const float* rp_ = Kd + (rowbase + (size_t)(c_) * 8 + (size_t)w) * NN; \
    char* lb_ = (char*)(&S[(c_) & 1][w][0]); \
    _Pragma("unroll") \
    for (int j_ = 0; j_ < 8; ++j_) { \
        __builtin_amdgcn_global_load_lds((GV*)(rp_ + (j_ * 64 + l) * 4), \
                                         (LV*)(lb_ + j_ * 1024), 16, 0, 0); \
    } } while (0)

    STAGE(0); STAGE(1);

    for (int it = 0; it < NUM_ITERS; ++it) {
        const bool last = (it == NUM_ITERS - 1);
        f4 sg[8];
        #pragma unroll
        for (int k = 0; k < 8; ++k) sg[k] = (f4){0.f, 0.f, 0.f, 0.f};

        for (int c = 0; c < 8; ++c) {
            if (last && c == 7) asm volatile("s_waitcnt vmcnt(0)" ::: "memory");
            else                asm volatile("s_waitcnt vmcnt(8)" ::: "memory");
            __builtin_amdgcn_sched_barrier(0);

            f4 kk[8];
            #pragma unroll
            for (int k = 0; k < 8; ++k) kk[k] = S[c & 1][w][(((w + k) & 7) << 6) + l];
            float dp = 0.f;
            #pragma unroll
            for (int k = 0; k < 8; ++k) dp += dotf4(kk[k], vbuf4[(((w + k) & 7) << 6) + l]);
            #pragma unroll
            for (int off = 32; off; off >>= 1) dp += __shfl_xor(dp, off);
            float uu = 1.0f / (dp + EPS_SINK);
            if (last && l == 0) uglob[rowbase + (size_t)c * 8 + w] = uu;
            #pragma unroll
            for (int k = 0; k < 8; ++k) sg[k] += uu * kk[k];

            if (!(last && c >= 6)) {
                asm volatile("s_waitcnt lgkmcnt(0)" ::: "memory");   // my ds_reads done
                __builtin_amdgcn_sched_barrier(0);
                STAGE((c + 2) & 7);    // wraps into next iteration's chunks 0,1
            }
        }

        // ---- sigma merge: 8 latin-square steps (disjoint regions per step) ----
        #pragma unroll
        for (int s = 0; s < 8; ++s) {
            int idx = (((w + s) & 7) << 6) + l;
            if (s == 0) sgbuf[idx] = sg[0];
            else        sgbuf[idx] += sg[s];
            __syncthreads();
        }

        // ---- block partial (8 KB) ----
        ((f4*)partial)[(size_t)q * 512 + t] = sgbuf[t];
        gbar(bar + ((size_t)it * 8 + b) * 32, t, 32u);

        // ---- slice v-reduce: block q produces f4-slots [g*16, g*16+16) ----
        {
            int c4 = g * 16 + (t & 15);
            int prow = t >> 4;     // 0..31
            f4 pv = ((const f4*)partial)[(size_t)(b * 32 + prow) * 512 + c4];
            #pragma unroll
            for (int off = 16; off <= 32; off <<= 1) {
                pv.x += __shfl_xor(pv.x, off);
                pv.y += __shfl_xor(pv.y, off);
                pv.z += __shfl_xor(pv.z, off);
                pv.w += __shfl_xor(pv.w, off);
            }
            if (l < 16) sgbuf[w * 16 + l] = pv;
            __syncthreads();
            if (t < 16) {
                f4 s = sgbuf[t];
                #pragma unroll
                for (int ww = 1; ww < 8; ww++) s += sgbuf[ww * 16 + t];
                f4 vv;
                vv.x = 1.0f / (s.x + EPS_SINK);
                vv.y = 1.0f / (s.y + EPS_SINK);
                vv.z = 1.0f / (s.z + EPS_SINK);
                vv.w = 1.0f / (s.w + EPS_SINK);
                ((f4*)vglob)[b * 512 + g * 16 + t] = vv;
            }
        }
        gbar(bar + ((size_t)(NUM_ITERS + it) * 8 + b) * 32, t, 32u);

        // ---- broadcast: reload full v for this batch ----
        vbuf4[t] = ((const f4*)vglob)[b * 512 + t];
        __syncthreads();
    }
#undef STAGE
}

// ---------------- argmax over columns of P = (u*K)*v (R2-proven) ----------------
__global__ __launch_bounds__(256) void argmax_k(const float* __restrict__ Kd,
                                                const float* __restrict__ u,
                                                const float* __restrict__ v,
                                                int* __restrict__ out) {
    int w = (blockIdx.x * 256 + threadIdx.x) >> 6;   // wave per row
    int lane = threadIdx.x & 63;
    int b = w >> 11, i = w & 2047;
    float uu = u[(size_t)b * NN + i];
    const float4* Kr = (const float4*)(Kd + ((size_t)b * NN + i) * NN);
    const float4* v4 = (const float4*)(v + (size_t)b * NN);
    float best = -1.0f;
    int bidx = 0;
    for (int it = 0; it < 8; it++) {
        int c4 = it * 64 + lane;
        float4 kk = Kr[c4];
        float4 vv = v4[c4];
        int j = c4 * 4;
        float p0 = (uu * kk.x) * vv.x;
        float p1 = (uu * kk.y) * vv.y;
        float p2 = (uu * kk.z) * vv.z;
        float p3 = (uu * kk.w) * vv.w;
        if (p0 > best) { best = p0; bidx = j; }
        if (p1 > best) { best = p1; bidx = j + 1; }
        if (p2 > best) { best = p2; bidx = j + 2; }
        if (p3 > best) { best = p3; bidx = j + 3; }
    }
    #pragma unroll
    for (int off = 32; off; off >>= 1) {
        float ov = __shfl_xor(best, off);
        int oi = __shfl_xor(bidx, off);
        if (ov > best || (ov == best && oi < bidx)) { best = ov; bidx = oi; }
    }
    if (lane == 0) out[(size_t)b * NN + i] = bidx;
}

extern "C" void kernel_launch(void* const* d_in, const int* in_sizes, int n_in,
                              void* d_out, int out_size, void* d_ws, size_t ws_size,
                              hipStream_t stream) {
    const float* x0 = (const float*)d_in[0];
    const float* x1 = (const float*)d_in[1];
    int* out = (int*)d_out;
    char* ws = (char*)d_ws;

    // ws layout (bytes), all 128-aligned
    float* Kd      = (float*)(ws + 0ull);                 // 134217728
    float* partial = (float*)(ws + 134217728ull);         // 2097152 (256 x 512 f4)
    float* vglob   = (float*)(ws + 136314880ull);         // 65536
    float* uglob   = (float*)(ws + 136380416ull);         // 65536
    float* sq0     = (float*)(ws + 136445952ull);         // 65536
    float* sq1     = (float*)(ws + 136511488ull);         // 65536
    unsigned* maxd = (unsigned*)(ws + 136577024ull);      // 128
    unsigned* bar  = (unsigned*)(ws + 136577152ull);      // 102400 (800 x 32 uints)

    init_k<<<100, 256, 0, stream>>>(maxd, bar);
    sq_k<<<8192, 256, 0, stream>>>(x0, x1, sq0, sq1);
    distc_k<0><<<4096, 256, 0, stream>>>(x0, x1, sq0, sq1, Kd, maxd);
    distc_k<1><<<4096, 256, 0, stream>>>(x0, x1, sq0, sq1, Kd, maxd);
    persist_k<<<256, 512, 0, stream>>>(Kd, partial, vglob, uglob, bar);
    argmax_k<<<4096, 256, 0, stream>>>(Kd, uglob, vglob, out);
}